// Round 1
// baseline (724.302 us; speedup 1.0000x reference)
//
#include <hip/hip_runtime.h>
#include <hip/hip_bf16.h>
#include <cstdint>

// Problem: B=4, T=2048, D=1024, H=16, HD=64.
// d_out = [ out (4,2048,1024) | k (4,16,2048,64) | v (4,16,2048,64) ] fp32.

typedef short bf16x8 __attribute__((ext_vector_type(8)));
typedef float f32x4 __attribute__((ext_vector_type(4)));

static __device__ __forceinline__ short f2b(float f) {
  union { float f; unsigned u; } x; x.f = f;
  unsigned r = (x.u + 0x7FFFu + ((x.u >> 16) & 1u)) >> 16;   // RNE
  return (short)r;
}

__global__ void cvt_f32_bf16(const float* __restrict__ src, short* __restrict__ dst, int n4) {
  int i = blockIdx.x * blockDim.x + threadIdx.x;
  if (i < n4) {
    float4 v = ((const float4*)src)[i];
    short4 o; o.x = f2b(v.x); o.y = f2b(v.y); o.z = f2b(v.z); o.w = f2b(v.w);
    ((short4*)dst)[i] = o;
  }
}

// C[M=8192][N=1024] = A[8192][1024] @ Bm[1024][1024]^T + bias, bf16 MFMA.
// MODE 0: Q -> bf16 [B,H,T,64]
// MODE 1: K -> fp32 [B,H,T,64] + bf16 [B,H,T,64]
// MODE 2: V -> fp32 [B,H,T,64] + bf16 transposed [B,H,64,T]
// MODE 3: O -> fp32 [M][N]
template <int MODE>
__global__ __launch_bounds__(256) void gemm_bt(
    const short* __restrict__ A, const short* __restrict__ Bm,
    const float* __restrict__ bias,
    float* __restrict__ out_f, short* __restrict__ out_b) {
  __shared__ short As[128 * 32];
  __shared__ short Bs[128 * 32];
  const int t = threadIdx.x;
  const int lane = t & 63;
  const int w = t >> 6;
  const int wm = w >> 1, wn = w & 1;
  const int quad = lane >> 4, l15 = lane & 15;
  const int bm = blockIdx.y, bn = blockIdx.x;

  f32x4 acc[4][4];
  for (int i = 0; i < 4; i++)
    for (int j = 0; j < 4; j++) acc[i][j] = (f32x4){0.f, 0.f, 0.f, 0.f};

  const int c0 = t, c1 = t + 256;
  const int r0 = c0 >> 2, cc0 = c0 & 3;
  const int r1 = c1 >> 2, cc1 = c1 & 3;

  for (int kk = 0; kk < 1024; kk += 32) {
    bf16x8 a0 = *(const bf16x8*)(A + (size_t)(bm * 128 + r0) * 1024 + kk + cc0 * 8);
    bf16x8 a1 = *(const bf16x8*)(A + (size_t)(bm * 128 + r1) * 1024 + kk + cc1 * 8);
    bf16x8 b0 = *(const bf16x8*)(Bm + (size_t)(bn * 128 + r0) * 1024 + kk + cc0 * 8);
    bf16x8 b1 = *(const bf16x8*)(Bm + (size_t)(bn * 128 + r1) * 1024 + kk + cc1 * 8);
    __syncthreads();
    *(bf16x8*)(As + r0 * 32 + cc0 * 8) = a0;
    *(bf16x8*)(As + r1 * 32 + cc1 * 8) = a1;
    *(bf16x8*)(Bs + r0 * 32 + cc0 * 8) = b0;
    *(bf16x8*)(Bs + r1 * 32 + cc1 * 8) = b1;
    __syncthreads();
    bf16x8 af[4], bfr[4];
    for (int mt = 0; mt < 4; mt++)
      af[mt] = *(const bf16x8*)(As + (wm * 64 + mt * 16 + l15) * 32 + quad * 8);
    for (int nt = 0; nt < 4; nt++)
      bfr[nt] = *(const bf16x8*)(Bs + (wn * 64 + nt * 16 + l15) * 32 + quad * 8);
    for (int mt = 0; mt < 4; mt++)
      for (int nt = 0; nt < 4; nt++)
        acc[mt][nt] = __builtin_amdgcn_mfma_f32_16x16x32_bf16(af[mt], bfr[nt], acc[mt][nt], 0, 0, 0);
  }

  for (int mt = 0; mt < 4; mt++) {
    const int row_base = bm * 128 + wm * 64 + mt * 16 + quad * 4;
    for (int nt = 0; nt < 4; nt++) {
      const int col = bn * 128 + wn * 64 + nt * 16 + l15;
      const float bb = bias[col];
      for (int r = 0; r < 4; r++) {
        const int row = row_base + r;
        const float v = acc[mt][nt][r] + bb;
        if (MODE == 3) {
          out_f[(size_t)row * 1024 + col] = v;
        } else {
          const int b = row >> 11, tt = row & 2047;
          const int h = col >> 6, hi = col & 63;
          const size_t idx = (((size_t)(b * 16 + h)) * 2048 + tt) * 64 + hi;
          if (MODE == 0) {
            out_b[idx] = f2b(v);
          } else if (MODE == 1) {
            out_f[idx] = v; out_b[idx] = f2b(v);
          } else {
            out_f[idx] = v;
            out_b[(((size_t)(b * 16 + h)) * 64 + hi) * 2048 + tt] = f2b(v);
          }
        }
      }
    }
  }
}

// Flash attention. Grid: (T/64, B*H). 4 waves/block; wave handles 16 queries.
// Q,K bf16 [B,H,T,64]; V bf16 transposed [B,H,64,T]; out bf16 [B*T][1024].
__global__ __launch_bounds__(256) void attn_fwd(
    const short* __restrict__ Qb, const short* __restrict__ Kb,
    const short* __restrict__ VTb, short* __restrict__ Ob) {
  __shared__ short Plds[4][16][32];
  const int t = threadIdx.x;
  const int w = t >> 6;
  const int lane = t & 63;
  const int quad = lane >> 4, l15 = lane & 15;
  const int bh = blockIdx.y;
  const int b = bh >> 4, h = bh & 15;
  const int q0 = blockIdx.x * 64 + w * 16;

  const short* Qh = Qb + (size_t)bh * 2048 * 64;
  const short* Kh = Kb + (size_t)bh * 2048 * 64;
  const short* VTh = VTb + (size_t)bh * 64 * 2048;

  const bf16x8 qf0 = *(const bf16x8*)(Qh + (q0 + l15) * 64 + quad * 8);
  const bf16x8 qf1 = *(const bf16x8*)(Qh + (q0 + l15) * 64 + quad * 8 + 32);

  float m_r[4], l_r[4];
  f32x4 o[4];
  for (int r = 0; r < 4; r++) { m_r[r] = -1e30f; l_r[r] = 0.f; }
  for (int nt = 0; nt < 4; nt++) o[nt] = (f32x4){0.f, 0.f, 0.f, 0.f};

  const int ntile = ((q0 + 15) >> 5) + 1;
  const float sscale = 0.125f * 1.4426950408889634f;  // scale * log2(e)

  for (int jt = 0; jt < ntile; ++jt) {
    const int j0 = jt * 32;
    f32x4 s[2];
    for (int si = 0; si < 2; ++si) {
      const int krow = j0 + si * 16 + l15;
      bf16x8 kf0 = *(const bf16x8*)(Kh + krow * 64 + quad * 8);
      bf16x8 kf1 = *(const bf16x8*)(Kh + krow * 64 + quad * 8 + 32);
      f32x4 z = (f32x4){0.f, 0.f, 0.f, 0.f};
      z = __builtin_amdgcn_mfma_f32_16x16x32_bf16(qf0, kf0, z, 0, 0, 0);
      z = __builtin_amdgcn_mfma_f32_16x16x32_bf16(qf1, kf1, z, 0, 0, 0);
      s[si] = z;
    }
    float sv[2][4];
    for (int si = 0; si < 2; si++) {
      const int kg = j0 + si * 16 + l15;
      for (int r = 0; r < 4; r++) {
        const int qg = q0 + quad * 4 + r;
        float x = s[si][r] * sscale;
        sv[si][r] = (kg > qg) ? -1e30f : x;
      }
    }
    float alpha[4], p[2][4];
    for (int r = 0; r < 4; r++) {
      float v = fmaxf(sv[0][r], sv[1][r]);
      v = fmaxf(v, __shfl_xor(v, 1));
      v = fmaxf(v, __shfl_xor(v, 2));
      v = fmaxf(v, __shfl_xor(v, 4));
      v = fmaxf(v, __shfl_xor(v, 8));
      const float mn = fmaxf(m_r[r], v);
      alpha[r] = exp2f(m_r[r] - mn);
      m_r[r] = mn;
      p[0][r] = exp2f(sv[0][r] - mn);
      p[1][r] = exp2f(sv[1][r] - mn);
      float ssum = p[0][r] + p[1][r];
      ssum += __shfl_xor(ssum, 1);
      ssum += __shfl_xor(ssum, 2);
      ssum += __shfl_xor(ssum, 4);
      ssum += __shfl_xor(ssum, 8);
      l_r[r] = l_r[r] * alpha[r] + ssum;
    }
    for (int nt = 0; nt < 4; nt++) {
      f32x4 t4 = o[nt];
      for (int r = 0; r < 4; r++) t4[r] *= alpha[r];
      o[nt] = t4;
    }
    for (int si = 0; si < 2; si++)
      for (int r = 0; r < 4; r++)
        Plds[w][quad * 4 + r][si * 16 + l15] = f2b(p[si][r]);
    // wave-private LDS round trip (C-layout -> A-layout); compiler inserts lgkmcnt
    bf16x8 pf = *(const bf16x8*)(&Plds[w][l15][quad * 8]);
    for (int nt = 0; nt < 4; nt++) {
      bf16x8 vf = *(const bf16x8*)(VTh + (nt * 16 + l15) * 2048 + j0 + quad * 8);
      o[nt] = __builtin_amdgcn_mfma_f32_16x16x32_bf16(pf, vf, o[nt], 0, 0, 0);
    }
  }
  for (int nt = 0; nt < 4; nt++) {
    const int col = h * 64 + nt * 16 + l15;
    for (int r = 0; r < 4; r++) {
      const int q = q0 + quad * 4 + r;
      Ob[((size_t)b * 2048 + q) * 1024 + col] = f2b(o[nt][r] / l_r[r]);
    }
  }
}

extern "C" void kernel_launch(void* const* d_in, const int* in_sizes, int n_in,
                              void* d_out, int out_size, void* d_ws, size_t ws_size,
                              hipStream_t stream) {
  const float* x  = (const float*)d_in[0];
  const float* Wq = (const float*)d_in[1];
  const float* bq = (const float*)d_in[2];
  const float* Wk = (const float*)d_in[3];
  const float* bk = (const float*)d_in[4];
  const float* Wv = (const float*)d_in[5];
  const float* bv = (const float*)d_in[6];
  const float* Wo = (const float*)d_in[7];
  const float* bo = (const float*)d_in[8];

  float* out   = (float*)d_out;
  float* k_out = out + (size_t)8388608;
  float* v_out = out + (size_t)16777216;

  short* ws  = (short*)d_ws;
  short* xb   = ws;                    // 8388608 elems
  short* wqb  = ws + 8388608;          // 1048576
  short* wkb  = ws + 9437184;
  short* wvb  = ws + 10485760;
  short* wob  = ws + 11534336;
  short* qb   = ws + 12582912;         // 8388608 [B,H,T,64]
  short* kb   = ws + 20971520;         // 8388608 [B,H,T,64]
  short* vtb  = ws + 29360128;         // 8388608 [B,H,64,T]
  short* attb = ws + 37748736;         // 8388608 [B*T,1024]

  cvt_f32_bf16<<<8192, 256, 0, stream>>>(x,  xb,  2097152);
  cvt_f32_bf16<<<1024, 256, 0, stream>>>(Wq, wqb, 262144);
  cvt_f32_bf16<<<1024, 256, 0, stream>>>(Wk, wkb, 262144);
  cvt_f32_bf16<<<1024, 256, 0, stream>>>(Wv, wvb, 262144);
  cvt_f32_bf16<<<1024, 256, 0, stream>>>(Wo, wob, 262144);

  dim3 g(8, 64), blk(256);
  gemm_bt<0><<<g, blk, 0, stream>>>(xb, wqb, bq, nullptr, qb);
  gemm_bt<1><<<g, blk, 0, stream>>>(xb, wkb, bk, k_out, kb);
  gemm_bt<2><<<g, blk, 0, stream>>>(xb, wvb, bv, v_out, vtb);

  attn_fwd<<<dim3(32, 64), 256, 0, stream>>>(qb, kb, vtb, attb);

  gemm_bt<3><<<g, blk, 0, stream>>>(attb, wob, bo, out, nullptr);
}